// Round 8
// baseline (61.466 us; speedup 1.0000x reference)
//
#include <hip/hip_runtime.h>
#include <hip/hip_bf16.h>
#include <hip/hip_fp16.h>

// TransformerEncoderReadout: only the picked atom's output row is needed.
//   QK[b,h,:] = (xp_b.Wq_h + bq_h).Wk_h^T * scale   (q.bk drops out of softmax)
//   s(i,h)    = x_i . QK[b,h,:]; softmax over i within molecule
//   WX[h,:]   = sum_i attn(i,h) x_i        (softmax sums to 1 -> bv folds out)
//   attn_out  = WX . WVO + (bv.Wo) + bo,   WVO_h = Wv_h . Wo_h
//   out_row   = LN2(h + FFN(h)),  h = LN1(xp + attn_out)
// R8: K1 computes QKh rows itself (self-sufficient role) -> K2 (per-molecule
// attention) streams NO weights; K3 batches the tail 4 rows/block so the
// packed fp16 weight streams are read 128x not 512x.

#define BMOL 512

typedef _Float16 v2h __attribute__((ext_vector_type(2)));

#if defined(__has_builtin)
#if __has_builtin(__builtin_amdgcn_fdot2)
#define HAVE_FDOT2 1
#endif
#endif
static __device__ __forceinline__ float fdot2f(v2h a, v2h b, float c) {
#ifdef HAVE_FDOT2
    return __builtin_amdgcn_fdot2(a, b, c, false);
#else
    return c + (float)a[0] * (float)b[0] + (float)a[1] * (float)b[1];
#endif
}

// ---------------- K1 block ranges ----------------
// [0,256) QKh rows | [256,384) WVOp | [384,416) W1p | [416,448) W2p
// [448,456) bvoP | [456,456+noff) offs
__global__ __launch_bounds__(256) void k_front(
    const float* __restrict__ AF, const float* __restrict__ Wq,
    const float* __restrict__ bq, const float* __restrict__ Wk,
    const float* __restrict__ Wv, const float* __restrict__ Wo,
    const float* __restrict__ bv, const float* __restrict__ W1,
    const float* __restrict__ W2,
    const int* __restrict__ mol, const int* __restrict__ picked,
    int N, int noff,
    int* __restrict__ offs, __half* __restrict__ QKh,
    __half* __restrict__ WVOp, float* __restrict__ bvoP,
    __half* __restrict__ W1p, __half* __restrict__ W2p)
{
    __shared__ float smf[12672];            // 50688 B, role-dependent layout
    __shared__ int rows[16];
    int bid = blockIdx.x, t = threadIdx.x;

    if (bid < 256) {
        // ---- QKh role: 16 molecules x 1 head; scale+bqk folded, fp16 out ----
        int h = bid >> 5, m0 = (bid & 31) * 16;
        float*  xp   = smf;                       // [16][128]
        __half* wkTh = (__half*)(smf + 2048);     // [128][132] fp16
        float*  q    = smf + 10496;               // [16][128]
        float*  bqks = smf + 12544;               // [128]
        const float scale = 0.08838834764831843f; // 1/sqrt(128)
        if (t < 16) {                       // lower_bound(mol, m) + picked
            int m = m0 + t;
            int lo = 0, hi = N;
            while (lo < hi) { int mid = (lo + hi) >> 1; if (mol[mid] < m) lo = mid + 1; else hi = mid; }
            rows[t] = lo + picked[m];
        }
        {                                   // Wk_h -> LDS transposed fp16 [kd][d]
            int d = t & 127, kc = t >> 7;
            #pragma unroll
            for (int i = 0; i < 16; ++i) {
                int kd0 = kc * 64 + i * 4;
                float4 v = *(const float4*)(Wk + (size_t)d * 1024 + h * 128 + kd0);
                wkTh[(kd0 + 0) * 132 + d] = (__half)v.x;
                wkTh[(kd0 + 1) * 132 + d] = (__half)v.y;
                wkTh[(kd0 + 2) * 132 + d] = (__half)v.z;
                wkTh[(kd0 + 3) * 132 + d] = (__half)v.w;
            }
        }
        __syncthreads();
        for (int p = t; p < 512; p += 256) {    // stage 16 picked rows
            int m = p >> 5, d4 = p & 31;
            ((float4*)(xp + m * 128))[d4] = ((const float4*)(AF + (size_t)rows[m] * 128))[d4];
        }
        if (t < 128) {                      // bqks[d] = sum_k bq[h,k]*WkT[k][d]
            float acc = 0.f;
            #pragma unroll 4
            for (int k = 0; k < 128; ++k) acc += bq[h * 128 + k] * (float)wkTh[k * 132 + t];
            bqks[t] = acc;
        }
        __syncthreads();
        int c = t & 127, mg = t >> 7;       // 8 mols per thread
        {                                   // q[m][c] = xp[m,:].Wq[:,h,c] + bq
            const float* wq = Wq + h * 128 + c;
            float acc[8] = {0.f,0.f,0.f,0.f,0.f,0.f,0.f,0.f};
            #pragma unroll 4
            for (int k = 0; k < 128; ++k) {
                float w = wq[(size_t)k * 1024];
                const float* xk = xp + (mg * 8) * 128 + k;
                #pragma unroll
                for (int j = 0; j < 8; ++j) acc[j] += xk[j * 128] * w;
            }
            float bb = bq[h * 128 + c];
            #pragma unroll
            for (int j = 0; j < 8; ++j) q[(mg * 8 + j) * 128 + c] = acc[j] + bb;
        }
        __syncthreads();
        {                                   // QKh[m][h*128+c] = (q[m,:].wkT[:,c]+bqks)*scale
            float acc[8] = {0.f,0.f,0.f,0.f,0.f,0.f,0.f,0.f};
            #pragma unroll 4
            for (int k = 0; k < 128; ++k) {
                float w = (float)wkTh[k * 132 + c];
                const float* qk = q + (mg * 8) * 128 + k;
                #pragma unroll
                for (int j = 0; j < 8; ++j) acc[j] += qk[j * 128] * w;
            }
            float bb = bqks[c];
            #pragma unroll
            for (int j = 0; j < 8; ++j)
                QKh[(size_t)(m0 + mg * 8 + j) * 1024 + h * 128 + c] = (__half)((acc[j] + bb) * scale);
        }
        return;
    }
    bid -= 256;
    if (bid < 128) {
        // ---- WVO tiled GEMM: per head C[d][c] = sum_kd Wv[d,h,kd]*Wo[h,kd,c] ----
        int h = bid >> 4, tile = bid & 15;
        int dt = tile >> 2, ct = tile & 3;
        float* Avs = smf;                   // [32][33]
        float* Bos = smf + 1056;            // [32][33]
        int ry = t >> 5, cx = t & 31;
        float acc[4] = {0.f, 0.f, 0.f, 0.f};
        for (int kk = 0; kk < 4; ++kk) {
            int r = t >> 3, e0 = (t & 7) * 4;
            float4 va = *(const float4*)(Wv + (size_t)(dt * 32 + r) * 1024 + h * 128 + kk * 32 + e0);
            Avs[r * 33 + e0] = va.x; Avs[r * 33 + e0 + 1] = va.y;
            Avs[r * 33 + e0 + 2] = va.z; Avs[r * 33 + e0 + 3] = va.w;
            float4 vb = *(const float4*)(Wo + (size_t)h * 16384 + (size_t)(kk * 32 + r) * 128 + ct * 32 + e0);
            Bos[r * 33 + e0] = vb.x; Bos[r * 33 + e0 + 1] = vb.y;
            Bos[r * 33 + e0 + 2] = vb.z; Bos[r * 33 + e0 + 3] = vb.w;
            __syncthreads();
            #pragma unroll
            for (int k = 0; k < 32; ++k) {
                float b = Bos[k * 33 + cx];
                #pragma unroll
                for (int i = 0; i < 4; ++i) acc[i] += Avs[(ry * 4 + i) * 33 + k] * b;
            }
            __syncthreads();
        }
        __half2 p0 = __floats2half2_rn(acc[0], acc[1]);
        __half2 p1 = __floats2half2_rn(acc[2], acc[3]);
        __half* dst = WVOp + (size_t)(h * 16 + dt * 4 + (ry >> 1)) * 1024
                           + (ct * 32 + cx) * 8 + (ry & 1) * 4;
        ((__half2*)dst)[0] = p0; ((__half2*)dst)[1] = p1;
        return;
    }
    bid -= 128;
    if (bid < 32) {                         // W1p[(k>>3)][f][k&7], K=128, F=512
        int g = bid * 256 + t;
        int kg = g >> 9, f = g & 511;
        __half2 p[4];
        #pragma unroll
        for (int j = 0; j < 4; ++j) {
            float a = W1[(size_t)(kg * 8 + 2 * j) * 512 + f];
            float b = W1[(size_t)(kg * 8 + 2 * j + 1) * 512 + f];
            p[j] = __floats2half2_rn(a, b);
        }
        *(float4*)(W1p + (size_t)kg * 4096 + f * 8) = *(float4*)p;
        return;
    }
    bid -= 32;
    if (bid < 32) {                         // W2p[(f>>3)][c][f&7], K=512, C=128
        int g = bid * 256 + t;
        int fg = g >> 7, c = g & 127;
        __half2 p[4];
        #pragma unroll
        for (int j = 0; j < 4; ++j) {
            float a = W2[(size_t)(fg * 8 + 2 * j) * 128 + c];
            float b = W2[(size_t)(fg * 8 + 2 * j + 1) * 128 + c];
            p[j] = __floats2half2_rn(a, b);
        }
        *(float4*)(W2p + (size_t)fg * 1024 + c * 8) = *(float4*)p;
        return;
    }
    bid -= 32;
    if (bid < 8) {                          // bvoP[j][c] = sum_{hk in j-th 128} bv[hk]*Wo[hk,c]
        int half = t >> 7, c = t & 127;
        float acc = 0.f;
        #pragma unroll 4
        for (int kk = 0; kk < 64; ++kk) {
            int k = bid * 128 + half * 64 + kk;
            acc += bv[k] * Wo[(size_t)k * 128 + c];
        }
        smf[half * 128 + c] = acc;
        __syncthreads();
        if (t < 128) bvoP[bid * 128 + t] = smf[t] + smf[128 + t];
        return;
    }
    bid -= 8;
    {                                       // offs scan
        int i = bid * 256 + t;
        if (i < N) {
            if (i == 0) { offs[0] = 0; offs[BMOL] = N; }
            else if (mol[i] != mol[i - 1]) offs[mol[i]] = i;
        }
    }
}

// ---------------- K2: pure attention, one block per molecule, no weights ----------------
__global__ __launch_bounds__(512) void k_attn(
    const float* __restrict__ AF, const int* __restrict__ offs,
    const __half* __restrict__ QKh, __half* __restrict__ WXg)
{
    int b = blockIdx.x, t = threadIdx.x;
    int o0 = offs[b], cnt = offs[b + 1] - o0;
    __shared__ __half xs[128][136];         // fp16 X; row = 272B = 17x16B
    __shared__ __half qsh[8][136];          // scaled QK row, fp16
    __shared__ float s[8 * 136];
    __shared__ float mh[8], lh[8];
    __shared__ float ws[2][1024];           // WX partials (i-split 2-way)

    const float4* af4 = (const float4*)(AF + (size_t)o0 * 128);
    for (int p = t; p < cnt * 32; p += 512) {   // stage X once, f32->f16
        int i = p >> 5, d4 = p & 31;
        float4 v = af4[p];
        float2 st;
        ((__half2*)&st)[0] = __floats2half2_rn(v.x, v.y);
        ((__half2*)&st)[1] = __floats2half2_rn(v.z, v.w);
        *(float2*)(&xs[i][d4 * 4]) = st;
    }
    if (t < 128) {                          // stage QKh row (1KB fp16)
        float4 ld = ((const float4*)(QKh + (size_t)b * 1024))[t];
        int h = t >> 4, d0 = (t & 15) * 8;
        *(float4*)(&qsh[h][d0]) = ld;
    }
    __syncthreads();
    for (int p = t; p < cnt * 8; p += 512) {    // scores, fp16 dot2
        int i = p >> 3, h = p & 7;
        const float4* xr = (const float4*)xs[i];
        const float4* qr = (const float4*)qsh[h];
        float acc = 0.f;
        #pragma unroll 8
        for (int dq = 0; dq < 16; ++dq) {
            float4 xraw = xr[dq], qraw = qr[dq];
            const v2h* xh2 = (const v2h*)&xraw;
            const v2h* qh2 = (const v2h*)&qraw;
            acc = fdot2f(xh2[0], qh2[0], acc);
            acc = fdot2f(xh2[1], qh2[1], acc);
            acc = fdot2f(xh2[2], qh2[2], acc);
            acc = fdot2f(xh2[3], qh2[3], acc);
        }
        s[h * 136 + i] = acc;
    }
    __syncthreads();
    {   // softmax stats: one 64-lane wave per head
        int h = t >> 6, lane = t & 63;
        float m = -1e30f;
        for (int i = lane; i < cnt; i += 64) m = fmaxf(m, s[h * 136 + i]);
        #pragma unroll
        for (int off = 32; off; off >>= 1) m = fmaxf(m, __shfl_xor(m, off));
        float l = 0.f;
        for (int i = lane; i < cnt; i += 64) l += __expf(s[h * 136 + i] - m);
        #pragma unroll
        for (int off = 32; off; off >>= 1) l += __shfl_xor(l, off);
        if (lane == 0) { mh[h] = m; lh[h] = 1.f / l; }
    }
    __syncthreads();
    for (int p = t; p < cnt * 8; p += 512) {
        int i = p >> 3, h = p & 7;
        s[h * 136 + i] = __expf(s[h * 136 + i] - mh[h]) * lh[h];
    }
    __syncthreads();
    {   // WX partials: thread = (ih, hw, qq); i interleaved 2-way
        int ih = t >> 8, hw = (t >> 5) & 7, qq = t & 31;
        float4 a4 = {0.f, 0.f, 0.f, 0.f};
        for (int i = ih; i < cnt; i += 2) {
            float sv = s[hw * 136 + i];
            float2 xraw = *(const float2*)(&xs[i][qq * 4]);
            const __half2* xh = (const __half2*)&xraw;
            float2 x0 = __half22float2(xh[0]), x1 = __half22float2(xh[1]);
            a4.x += sv * x0.x; a4.y += sv * x0.y; a4.z += sv * x1.x; a4.w += sv * x1.y;
        }
        *(float4*)(&ws[ih][hw * 128 + qq * 4]) = a4;
    }
    __syncthreads();
    {   // merge partials -> fp16 -> global (stride-2 LDS reads: 2-way, free)
        int k0 = t * 2;
        float v0 = ws[0][k0] + ws[1][k0];
        float v1 = ws[0][k0 + 1] + ws[1][k0 + 1];
        ((__half2*)(WXg + (size_t)b * 1024))[t] = __floats2half2_rn(v0, v1);
    }
}

// ---------------- K3: batched tail, 4 molecules per block ----------------
__global__ __launch_bounds__(512) void k_tail(
    const float* __restrict__ AF, const int* __restrict__ offs,
    const int* __restrict__ picked, const __half* __restrict__ WXg,
    const __half* __restrict__ WVOp, const float* __restrict__ bvoP,
    const float* __restrict__ bo,
    const float* __restrict__ g1, const float* __restrict__ be1,
    const __half* __restrict__ W1p, const float* __restrict__ b1,
    const __half* __restrict__ W2p, const float* __restrict__ b2,
    const float* __restrict__ g2, const float* __restrict__ be2,
    float* __restrict__ out)
{
    int r0 = blockIdx.x * 4, t = threadIdx.x;
    __shared__ __half wsh4[4][1024];        // 8 KB WX rows
    __shared__ float  xp4[4][128];          // residual rows
    __shared__ float  h1raw[4][128];
    __shared__ float  h1nf[4][128];
    __shared__ __half h1nh[4][128];
    __shared__ __half msh4[4][512];
    __shared__ float  h2raw[4][128];
    {   // load 4 WX rows (one float4 per thread)
        int rr = t >> 7, cc = t & 127;
        ((float4*)(wsh4[rr]))[cc] = ((const float4*)(WXg + (size_t)(r0 + rr) * 1024))[cc];
    }
    if (t < 128) {                          // load 4 residual rows
        int rr = t >> 5, d4 = t & 31;
        int row = offs[r0 + rr] + picked[r0 + rr];
        ((float4*)(xp4[rr]))[d4] = ((const float4*)(AF + (size_t)row * 128))[d4];
    }
    __syncthreads();
    int row = t >> 7, c = t & 127;
    {   // phase A: attn_out = wsh4[row] . WVO[:,c]  (K=1024)
        const __half* wp = WVOp + (size_t)c * 8;
        const v2h* wk = (const v2h*)wsh4[row];
        float acc = 0.f;
        #pragma unroll 8
        for (int kg = 0; kg < 128; ++kg) {
            float4 raw = *(const float4*)(wp + (size_t)kg * 1024);
            const v2h* hp = (const v2h*)&raw;
            acc = fdot2f(hp[0], wk[kg * 4 + 0], acc);
            acc = fdot2f(hp[1], wk[kg * 4 + 1], acc);
            acc = fdot2f(hp[2], wk[kg * 4 + 2], acc);
            acc = fdot2f(hp[3], wk[kg * 4 + 3], acc);
        }
        float bias = bo[c];
        #pragma unroll
        for (int j = 0; j < 8; ++j) bias += bvoP[j * 128 + c];
        h1raw[row][c] = acc + bias + xp4[row][c];
    }
    __syncthreads();
    {   // LN1: waves 0-3, one row each
        int wv = t >> 6, lane = t & 63;
        if (wv < 4) {
            float a = h1raw[wv][lane], bb = h1raw[wv][lane + 64];
            float sm = a + bb, sq = a * a + bb * bb;
            #pragma unroll
            for (int off = 32; off; off >>= 1) { sm += __shfl_xor(sm, off); sq += __shfl_xor(sq, off); }
            float m = sm * (1.f / 128.f), var = sq * (1.f / 128.f) - m * m;
            float rs = rsqrtf(var + 1e-3f);
            float va = (a - m) * rs * g1[lane] + be1[lane];
            float vb = (bb - m) * rs * g1[lane + 64] + be1[lane + 64];
            h1nf[wv][lane] = va;      h1nh[wv][lane] = (__half)va;
            h1nf[wv][lane + 64] = vb; h1nh[wv][lane + 64] = (__half)vb;
        }
    }
    __syncthreads();
    {   // phase B: msh4[r][f] = relu(h1nh[r] . W1[:,f] + b1), f = t, 4 rows/thread
        const __half* wp = W1p + t * 8;
        float acc[4] = {0.f, 0.f, 0.f, 0.f};
        #pragma unroll 4
        for (int kg = 0; kg < 16; ++kg) {
            float4 raw = *(const float4*)(wp + (size_t)kg * 4096);
            const v2h* hp = (const v2h*)&raw;
            #pragma unroll
            for (int j = 0; j < 4; ++j) {
                #pragma unroll
                for (int r = 0; r < 4; ++r)
                    acc[r] = fdot2f(hp[j], ((const v2h*)h1nh[r])[kg * 4 + j], acc[r]);
            }
        }
        float bb = b1[t];
        #pragma unroll
        for (int r = 0; r < 4; ++r) msh4[r][t] = (__half)fmaxf(acc[r] + bb, 0.f);
    }
    __syncthreads();
    {   // phase C: h2 = msh4[row] . W2[:,c] + b2 + h1n  (K=512)
        const __half* wp = W2p + (size_t)c * 8;
        const v2h* mk = (const v2h*)msh4[row];
        float acc = 0.f;
        #pragma unroll 8
        for (int kg = 0; kg < 64; ++kg) {
            float4 raw = *(const float4*)(wp + (size_t)kg * 1024);
            const v2h* hp = (const v2h*)&raw;
            acc = fdot2f(hp[0], mk[kg * 4 + 0], acc);
            acc = fdot2f(hp[1], mk[kg * 4 + 1], acc);
            acc = fdot2f(hp[2], mk[kg * 4 + 2], acc);
            acc = fdot2f(hp[3], mk[kg * 4 + 3], acc);
        }
        h2raw[row][c] = acc + b2[c] + h1nf[row][c];
    }
    __syncthreads();
    {   // LN2: waves 0-3 -> out
        int wv = t >> 6, lane = t & 63;
        if (wv < 4) {
            float a = h2raw[wv][lane], bb = h2raw[wv][lane + 64];
            float sm = a + bb, sq = a * a + bb * bb;
            #pragma unroll
            for (int off = 32; off; off >>= 1) { sm += __shfl_xor(sm, off); sq += __shfl_xor(sq, off); }
            float m = sm * (1.f / 128.f), var = sq * (1.f / 128.f) - m * m;
            float rs = rsqrtf(var + 1e-3f);
            out[(size_t)(r0 + wv) * 128 + lane]      = (a - m) * rs * g2[lane] + be2[lane];
            out[(size_t)(r0 + wv) * 128 + lane + 64] = (bb - m) * rs * g2[lane + 64] + be2[lane + 64];
        }
    }
}

extern "C" void kernel_launch(void* const* d_in, const int* in_sizes, int n_in,
                              void* d_out, int out_size, void* d_ws, size_t ws_size,
                              hipStream_t stream) {
    const float* AF  = (const float*)d_in[0];
    const float* Wq  = (const float*)d_in[1];
    const float* bq  = (const float*)d_in[2];
    const float* Wk  = (const float*)d_in[3];
    const float* Wv  = (const float*)d_in[5];
    const float* bv  = (const float*)d_in[6];
    const float* Wo  = (const float*)d_in[7];
    const float* bo  = (const float*)d_in[8];
    const float* W1  = (const float*)d_in[9];
    const float* b1  = (const float*)d_in[10];
    const float* W2  = (const float*)d_in[11];
    const float* b2  = (const float*)d_in[12];
    const float* g1  = (const float*)d_in[13];
    const float* be1 = (const float*)d_in[14];
    const float* g2  = (const float*)d_in[15];
    const float* be2 = (const float*)d_in[16];
    const int* mol    = (const int*)d_in[17];
    const int* picked = (const int*)d_in[18];
    int N = in_sizes[0] / 128;
    int noff = (N + 255) / 256;

    char* ws = (char*)d_ws;
    int*    offs = (int*)ws;                      // 513 ints (4KB slot)
    __half* WVOp = (__half*)(ws + 4096);          // packed [128][128][8] 256KB
    float*  bvoP = (float*)(ws + 266240);         // [8][128] 4KB
    __half* W1p  = (__half*)(ws + 270336);        // packed [16][512][8] 128KB
    __half* W2p  = (__half*)(ws + 401408);        // packed [64][128][8] 128KB
    __half* QKh  = (__half*)(ws + 532480);        // [512][1024] fp16 1MB
    __half* WXg  = (__half*)(ws + 1581056);       // [512][1024] fp16 1MB

    k_front<<<456 + noff, 256, 0, stream>>>(AF, Wq, bq, Wk, Wv, Wo, bv, W1, W2,
                                            mol, picked, N, noff,
                                            offs, QKh, WVOp, bvoP, W1p, W2p);
    k_attn<<<BMOL, 512, 0, stream>>>(AF, offs, QKh, WXg);
    k_tail<<<128, 512, 0, stream>>>(AF, offs, picked, WXg, WVOp, bvoP, bo,
                                    g1, be1, W1p, b1, W2p, b2, g2, be2,
                                    (float*)d_out);
}

// Round 9
// 45.196 us; speedup vs baseline: 1.3600x; 1.3600x over previous
//
#include <hip/hip_runtime.h>
#include <hip/hip_bf16.h>
#include <hip/hip_fp16.h>

// TransformerEncoderReadout: only the picked atom's output row is needed.
//   QK[b,h,:] = xp_b . WQK_h + bqk_h,   WQK_h = Wq_h . Wk_h^T  (q.bk drops out)
//   s(i,h)    = x_i . QK[b,h,:] / sqrt(128); softmax over i within molecule
//   WX[h,:]   = sum_i attn(i,h) x_i      (softmax sums to 1 -> bv folds out)
//   attn_out  = WX . WVO + (bv.Wo) + bo, WVO_h = Wv_h . Wo_h
//   out_row   = LN2(h + FFN(h)),  h = LN1(xp + attn_out)
// R9 = R7 structure + tail split out (R8's only sound piece):
//   K1: fused-weight tile GEMMs + packing (R7 verbatim; fast, coalesced).
//   K2: attention incl. QK row from WQKp (weight stream 256KB/block, not 768KB).
//   K3: batched tail 4 rows/block (weight streams read 128x, not 512x).

#define BMOL 512

typedef _Float16 v2h __attribute__((ext_vector_type(2)));

#if defined(__has_builtin)
#if __has_builtin(__builtin_amdgcn_fdot2)
#define HAVE_FDOT2 1
#endif
#endif
static __device__ __forceinline__ float fdot2f(v2h a, v2h b, float c) {
#ifdef HAVE_FDOT2
    return __builtin_amdgcn_fdot2(a, b, c, false);
#else
    return c + (float)a[0] * (float)b[0] + (float)a[1] * (float)b[1];
#endif
}

// ---------------- K1 block ranges ----------------
// [0,128) WVOp | [128,256) WQKp | [256,288) W1p | [288,320) W2p
// [320,328) bvoP | [328,336) bqk | [336,336+noff) offs
__global__ __launch_bounds__(256) void k_front(
    const float* __restrict__ Wq, const float* __restrict__ bq,
    const float* __restrict__ Wk, const float* __restrict__ Wv,
    const float* __restrict__ Wo, const float* __restrict__ bv,
    const float* __restrict__ W1, const float* __restrict__ W2,
    const int* __restrict__ mol, int N, int noff,
    int* __restrict__ offs, __half* __restrict__ WVOp,
    __half* __restrict__ WQKp, float* __restrict__ bqk,
    float* __restrict__ bvoP, __half* __restrict__ W1p, __half* __restrict__ W2p)
{
    __shared__ float lds[2176];             // 2x [32][33] tiles
    int bid = blockIdx.x, t = threadIdx.x;

    if (bid < 256) {
        // ---- tiled GEMM: 32x32 output tile, K=128 ----
        // bid<128: WVO[(h*128+d)][c] = sum_kd Wv[d,h,kd]*Wo[h,kd,c]
        // else   : WQK[(h*128+k)][d] = sum_kd Wq[k,h,kd]*Wk[d,h,kd]
        bool qk = bid >= 128;
        int rel = bid & 127;
        int h = rel >> 4, tile = rel & 15;
        int dt = tile >> 2, ct = tile & 3;
        float* Avs = lds;                   // [32][33]
        float* Bos = lds + 1056;            // [32][33]
        int ry = t >> 5, cx = t & 31;
        float acc[4] = {0.f, 0.f, 0.f, 0.f};
        const float* Asrc = qk ? Wq : Wv;
        for (int kk = 0; kk < 4; ++kk) {
            int r = t >> 3, e0 = (t & 7) * 4;
            float4 va = *(const float4*)(Asrc + (size_t)(dt * 32 + r) * 1024 + h * 128 + kk * 32 + e0);
            Avs[r * 33 + e0] = va.x; Avs[r * 33 + e0 + 1] = va.y;
            Avs[r * 33 + e0 + 2] = va.z; Avs[r * 33 + e0 + 3] = va.w;
            if (qk) {                       // B[kd][d] = Wk[d,h,kd] (transposed load)
                float4 vb = *(const float4*)(Wk + (size_t)(ct * 32 + r) * 1024 + h * 128 + kk * 32 + e0);
                Bos[(e0 + 0) * 33 + r] = vb.x;
                Bos[(e0 + 1) * 33 + r] = vb.y;
                Bos[(e0 + 2) * 33 + r] = vb.z;
                Bos[(e0 + 3) * 33 + r] = vb.w;
            } else {                        // B[kd][c] = Wo[h,kd,c]
                float4 vb = *(const float4*)(Wo + (size_t)h * 16384 + (size_t)(kk * 32 + r) * 128 + ct * 32 + e0);
                Bos[r * 33 + e0] = vb.x; Bos[r * 33 + e0 + 1] = vb.y;
                Bos[r * 33 + e0 + 2] = vb.z; Bos[r * 33 + e0 + 3] = vb.w;
            }
            __syncthreads();
            #pragma unroll
            for (int k = 0; k < 32; ++k) {
                float b = Bos[k * 33 + cx];
                #pragma unroll
                for (int i = 0; i < 4; ++i) acc[i] += Avs[(ry * 4 + i) * 33 + k] * b;
            }
            __syncthreads();
        }
        // packed [k>>3][c][k&7]: k = h*128 + dt*32 + ry*4 + i; c = ct*32+cx
        __half2 p0 = __floats2half2_rn(acc[0], acc[1]);
        __half2 p1 = __floats2half2_rn(acc[2], acc[3]);
        __half* dst = (qk ? WQKp : WVOp)
                    + (size_t)(h * 16 + dt * 4 + (ry >> 1)) * 1024
                    + (ct * 32 + cx) * 8 + (ry & 1) * 4;
        ((__half2*)dst)[0] = p0; ((__half2*)dst)[1] = p1;
        return;
    }
    bid -= 256;
    if (bid < 32) {                         // W1p[(k>>3)][f][k&7], K=128, F=512
        int g = bid * 256 + t;
        int kg = g >> 9, f = g & 511;
        __half2 p[4];
        #pragma unroll
        for (int j = 0; j < 4; ++j) {
            float a = W1[(size_t)(kg * 8 + 2 * j) * 512 + f];
            float b = W1[(size_t)(kg * 8 + 2 * j + 1) * 512 + f];
            p[j] = __floats2half2_rn(a, b);
        }
        *(float4*)(W1p + (size_t)kg * 4096 + f * 8) = *(float4*)p;
        return;
    }
    bid -= 32;
    if (bid < 32) {                         // W2p[(f>>3)][c][f&7], K=512, C=128
        int g = bid * 256 + t;
        int fg = g >> 7, c = g & 127;
        __half2 p[4];
        #pragma unroll
        for (int j = 0; j < 4; ++j) {
            float a = W2[(size_t)(fg * 8 + 2 * j) * 128 + c];
            float b = W2[(size_t)(fg * 8 + 2 * j + 1) * 128 + c];
            p[j] = __floats2half2_rn(a, b);
        }
        *(float4*)(W2p + (size_t)fg * 1024 + c * 8) = *(float4*)p;
        return;
    }
    bid -= 32;
    if (bid < 8) {                          // bvoP[j][c] = sum_{hk in j-th 128} bv[hk]*Wo[hk,c]
        int half = t >> 7, c = t & 127;
        float acc = 0.f;
        #pragma unroll 4
        for (int kk = 0; kk < 64; ++kk) {
            int k = bid * 128 + half * 64 + kk;
            acc += bv[k] * Wo[(size_t)k * 128 + c];
        }
        lds[half * 128 + c] = acc;
        __syncthreads();
        if (t < 128) bvoP[bid * 128 + t] = lds[t] + lds[128 + t];
        return;
    }
    bid -= 8;
    if (bid < 8) {                          // bqk[h][d] = sum_kd bq[h,kd]*Wk[d,h,kd]
        int h = bid;
        if (t < 128) {
            const float* wk = Wk + (size_t)t * 1024 + h * 128;
            const float* bqh = bq + h * 128;
            float acc = 0.f;
            #pragma unroll 4
            for (int kd = 0; kd < 128; ++kd) acc += bqh[kd] * wk[kd];
            bqk[h * 128 + t] = acc;
        }
        return;
    }
    bid -= 8;
    {                                       // offs scan
        int i = bid * 256 + t;
        if (i < N) {
            if (i == 0) { offs[0] = 0; offs[BMOL] = N; }
            else if (mol[i] != mol[i - 1]) offs[mol[i]] = i;
        }
    }
}

// ---------------- K2: attention (QK row + scores + softmax + WX), 1 block/mol ----------------
__global__ __launch_bounds__(512) void k_attn(
    const float* __restrict__ AF, const int* __restrict__ offs,
    const int* __restrict__ picked,
    const __half* __restrict__ WQKp, const float* __restrict__ bqk,
    __half* __restrict__ WXg)
{
    int b = blockIdx.x, t = threadIdx.x;
    int o0 = offs[b], cnt = offs[b + 1] - o0;
    __shared__ __half xs[128][136];         // fp16 X; row = 272B = 17x16B
    __shared__ __half qsh[8][136];          // scaled QK row, fp16
    __shared__ float s[8 * 136];
    __shared__ float mh[8], lh[8];
    __shared__ float ws[2][1024];           // WX partials (i-split 2-way)
    __shared__ __half xph[128];             // picked row fp16
    const float scale = 0.08838834764831843f;   // 1/sqrt(128)

    const float4* af4 = (const float4*)(AF + (size_t)o0 * 128);
    for (int p = t; p < cnt * 32; p += 512) {   // stage X once, f32->f16
        int i = p >> 5, d4 = p & 31;
        float4 v = af4[p];
        float2 st;
        ((__half2*)&st)[0] = __floats2half2_rn(v.x, v.y);
        ((__half2*)&st)[1] = __floats2half2_rn(v.z, v.w);
        *(float2*)(&xs[i][d4 * 4]) = st;
    }
    if (t < 128) xph[t] = (__half)AF[(size_t)(o0 + picked[b]) * 128 + t];
    __syncthreads();
    {   // ---- QK row: qsh[h][d] = (xph . WQK_h[:,d] + bqk)*scale ----
        int h = t >> 6, d0 = (t & 63) * 2;
        const __half* wp = WQKp + ((size_t)(h * 16) * 128 + d0) * 8;
        const v2h* xh = (const v2h*)xph;    // broadcast reads (wave-uniform addr)
        float a0 = 0.f, a1 = 0.f;
        #pragma unroll 4
        for (int kg = 0; kg < 16; ++kg) {
            float4 r0 = *(const float4*)(wp + (size_t)kg * 1024);
            float4 r1 = *(const float4*)(wp + (size_t)kg * 1024 + 8);
            const v2h* h0 = (const v2h*)&r0;
            const v2h* h1 = (const v2h*)&r1;
            #pragma unroll
            for (int j = 0; j < 4; ++j) {
                v2h xv = xh[kg * 4 + j];
                a0 = fdot2f(xv, h0[j], a0);
                a1 = fdot2f(xv, h1[j], a1);
            }
        }
        qsh[h][d0]     = (__half)((a0 + bqk[h * 128 + d0]) * scale);
        qsh[h][d0 + 1] = (__half)((a1 + bqk[h * 128 + d0 + 1]) * scale);
    }
    __syncthreads();
    for (int p = t; p < cnt * 8; p += 512) {    // scores, fp16 dot2
        int i = p >> 3, h = p & 7;
        const float4* xr = (const float4*)xs[i];
        const float4* qr = (const float4*)qsh[h];
        float acc = 0.f;
        #pragma unroll 8
        for (int dq = 0; dq < 16; ++dq) {
            float4 xraw = xr[dq], qraw = qr[dq];
            const v2h* xh2 = (const v2h*)&xraw;
            const v2h* qh2 = (const v2h*)&qraw;
            acc = fdot2f(xh2[0], qh2[0], acc);
            acc = fdot2f(xh2[1], qh2[1], acc);
            acc = fdot2f(xh2[2], qh2[2], acc);
            acc = fdot2f(xh2[3], qh2[3], acc);
        }
        s[h * 136 + i] = acc;
    }
    __syncthreads();
    {   // softmax stats: one 64-lane wave per head
        int h = t >> 6, lane = t & 63;
        float m = -1e30f;
        for (int i = lane; i < cnt; i += 64) m = fmaxf(m, s[h * 136 + i]);
        #pragma unroll
        for (int off = 32; off; off >>= 1) m = fmaxf(m, __shfl_xor(m, off));
        float l = 0.f;
        for (int i = lane; i < cnt; i += 64) l += __expf(s[h * 136 + i] - m);
        #pragma unroll
        for (int off = 32; off; off >>= 1) l += __shfl_xor(l, off);
        if (lane == 0) { mh[h] = m; lh[h] = 1.f / l; }
    }
    __syncthreads();
    for (int p = t; p < cnt * 8; p += 512) {
        int i = p >> 3, h = p & 7;
        s[h * 136 + i] = __expf(s[h * 136 + i] - mh[h]) * lh[h];
    }
    __syncthreads();
    {   // WX partials: thread = (ih, hw, qq); i interleaved 2-way
        int ih = t >> 8, hw = (t >> 5) & 7, qq = t & 31;
        float4 a4 = {0.f, 0.f, 0.f, 0.f};
        for (int i = ih; i < cnt; i += 2) {
            float sv = s[hw * 136 + i];
            float2 xraw = *(const float2*)(&xs[i][qq * 4]);
            const __half2* xh = (const __half2*)&xraw;
            float2 x0 = __half22float2(xh[0]), x1 = __half22float2(xh[1]);
            a4.x += sv * x0.x; a4.y += sv * x0.y; a4.z += sv * x1.x; a4.w += sv * x1.y;
        }
        *(float4*)(&ws[ih][hw * 128 + qq * 4]) = a4;
    }
    __syncthreads();
    {   // merge partials -> fp16 -> global (stride-2 LDS reads: 2-way, free)
        int k0 = t * 2;
        float v0 = ws[0][k0] + ws[1][k0];
        float v1 = ws[0][k0 + 1] + ws[1][k0 + 1];
        ((__half2*)(WXg + (size_t)b * 1024))[t] = __floats2half2_rn(v0, v1);
    }
}

// ---------------- K3: batched tail, 4 molecules per block ----------------
__global__ __launch_bounds__(512) void k_tail(
    const float* __restrict__ AF, const int* __restrict__ offs,
    const int* __restrict__ picked, const __half* __restrict__ WXg,
    const __half* __restrict__ WVOp, const float* __restrict__ bvoP,
    const float* __restrict__ bo,
    const float* __restrict__ g1, const float* __restrict__ be1,
    const __half* __restrict__ W1p, const float* __restrict__ b1,
    const __half* __restrict__ W2p, const float* __restrict__ b2,
    const float* __restrict__ g2, const float* __restrict__ be2,
    float* __restrict__ out)
{
    int r0 = blockIdx.x * 4, t = threadIdx.x;
    __shared__ __half wsh4[4][1024];        // 8 KB WX rows
    __shared__ float  xp4[4][128];          // residual rows
    __shared__ float  h1raw[4][128];
    __shared__ float  h1nf[4][128];
    __shared__ __half h1nh[4][128];
    __shared__ __half msh4[4][512];
    __shared__ float  h2raw[4][128];
    {   // load 4 WX rows (one float4 per thread)
        int rr = t >> 7, cc = t & 127;
        ((float4*)(wsh4[rr]))[cc] = ((const float4*)(WXg + (size_t)(r0 + rr) * 1024))[cc];
    }
    if (t < 128) {                          // load 4 residual rows
        int rr = t >> 5, d4 = t & 31;
        int row = offs[r0 + rr] + picked[r0 + rr];
        ((float4*)(xp4[rr]))[d4] = ((const float4*)(AF + (size_t)row * 128))[d4];
    }
    __syncthreads();
    int row = t >> 7, c = t & 127;
    {   // phase A: attn_out = wsh4[row] . WVO[:,c]  (K=1024)
        const __half* wp = WVOp + (size_t)c * 8;
        const v2h* wk = (const v2h*)wsh4[row];
        float acc = 0.f;
        #pragma unroll 8
        for (int kg = 0; kg < 128; ++kg) {
            float4 raw = *(const float4*)(wp + (size_t)kg * 1024);
            const v2h* hp = (const v2h*)&raw;
            acc = fdot2f(hp[0], wk[kg * 4 + 0], acc);
            acc = fdot2f(hp[1], wk[kg * 4 + 1], acc);
            acc = fdot2f(hp[2], wk[kg * 4 + 2], acc);
            acc = fdot2f(hp[3], wk[kg * 4 + 3], acc);
        }
        float bias = bo[c];
        #pragma unroll
        for (int j = 0; j < 8; ++j) bias += bvoP[j * 128 + c];
        h1raw[row][c] = acc + bias + xp4[row][c];
    }
    __syncthreads();
    {   // LN1: waves 0-3, one row each
        int wv = t >> 6, lane = t & 63;
        if (wv < 4) {
            float a = h1raw[wv][lane], bb = h1raw[wv][lane + 64];
            float sm = a + bb, sq = a * a + bb * bb;
            #pragma unroll
            for (int off = 32; off; off >>= 1) { sm += __shfl_xor(sm, off); sq += __shfl_xor(sq, off); }
            float m = sm * (1.f / 128.f), var = sq * (1.f / 128.f) - m * m;
            float rs = rsqrtf(var + 1e-3f);
            float va = (a - m) * rs * g1[lane] + be1[lane];
            float vb = (bb - m) * rs * g1[lane + 64] + be1[lane + 64];
            h1nf[wv][lane] = va;      h1nh[wv][lane] = (__half)va;
            h1nf[wv][lane + 64] = vb; h1nh[wv][lane + 64] = (__half)vb;
        }
    }
    __syncthreads();
    {   // phase B: msh4[r][f] = relu(h1nh[r] . W1[:,f] + b1), f = t, 4 rows/thread
        const __half* wp = W1p + t * 8;
        float acc[4] = {0.f, 0.f, 0.f, 0.f};
        #pragma unroll 4
        for (int kg = 0; kg < 16; ++kg) {
            float4 raw = *(const float4*)(wp + (size_t)kg * 4096);
            const v2h* hp = (const v2h*)&raw;
            #pragma unroll
            for (int j = 0; j < 4; ++j) {
                #pragma unroll
                for (int r = 0; r < 4; ++r)
                    acc[r] = fdot2f(hp[j], ((const v2h*)h1nh[r])[kg * 4 + j], acc[r]);
            }
        }
        float bb = b1[t];
        #pragma unroll
        for (int r = 0; r < 4; ++r) msh4[r][t] = (__half)fmaxf(acc[r] + bb, 0.f);
    }
    __syncthreads();
    {   // phase C: h2 = msh4[row] . W2[:,c] + b2 + h1n  (K=512)
        const __half* wp = W2p + (size_t)c * 8;
        const v2h* mk = (const v2h*)msh4[row];
        float acc = 0.f;
        #pragma unroll 8
        for (int kg = 0; kg < 64; ++kg) {
            float4 raw = *(const float4*)(wp + (size_t)kg * 1024);
            const v2h* hp = (const v2h*)&raw;
            acc = fdot2f(hp[0], mk[kg * 4 + 0], acc);
            acc = fdot2f(hp[1], mk[kg * 4 + 1], acc);
            acc = fdot2f(hp[2], mk[kg * 4 + 2], acc);
            acc = fdot2f(hp[3], mk[kg * 4 + 3], acc);
        }
        h2raw[row][c] = acc + b2[c] + h1nf[row][c];
    }
    __syncthreads();
    {   // LN2: waves 0-3 -> out
        int wv = t >> 6, lane = t & 63;
        if (wv < 4) {
            float a = h2raw[wv][lane], bb = h2raw[wv][lane + 64];
            float sm = a + bb, sq = a * a + bb * bb;
            #pragma unroll
            for (int off = 32; off; off >>= 1) { sm += __shfl_xor(sm, off); sq += __shfl_xor(sq, off); }
            float m = sm * (1.f / 128.f), var = sq * (1.f / 128.f) - m * m;
            float rs = rsqrtf(var + 1e-3f);
            out[(size_t)(r0 + wv) * 128 + lane]      = (a - m) * rs * g2[lane] + be2[lane];
            out[(size_t)(r0 + wv) * 128 + lane + 64] = (bb - m) * rs * g2[lane + 64] + be2[lane + 64];
        }
    }
}

extern "C" void kernel_launch(void* const* d_in, const int* in_sizes, int n_in,
                              void* d_out, int out_size, void* d_ws, size_t ws_size,
                              hipStream_t stream) {
    const float* AF  = (const float*)d_in[0];
    const float* Wq  = (const float*)d_in[1];
    const float* bq  = (const float*)d_in[2];
    const float* Wk  = (const float*)d_in[3];
    const float* Wv  = (const float*)d_in[5];
    const float* bv  = (const float*)d_in[6];
    const float* Wo  = (const float*)d_in[7];
    const float* bo  = (const float*)d_in[8];
    const float* W1  = (const float*)d_in[9];
    const float* b1  = (const float*)d_in[10];
    const float* W2  = (const float*)d_in[11];
    const float* b2  = (const float*)d_in[12];
    const float* g1  = (const float*)d_in[13];
    const float* be1 = (const float*)d_in[14];
    const float* g2  = (const float*)d_in[15];
    const float* be2 = (const float*)d_in[16];
    const int* mol    = (const int*)d_in[17];
    const int* picked = (const int*)d_in[18];
    int N = in_sizes[0] / 128;
    int noff = (N + 255) / 256;

    char* ws = (char*)d_ws;
    int*    offs = (int*)ws;                      // 513 ints (4KB slot)
    __half* WVOp = (__half*)(ws + 4096);          // packed [128][128][8] 256KB
    __half* WQKp = (__half*)(ws + 266240);        // packed [128][128][8] 256KB
    float*  bqk  = (float*)(ws + 528384);         // [8][128] 4KB
    float*  bvoP = (float*)(ws + 532480);         // [8][128] 4KB
    __half* W1p  = (__half*)(ws + 536576);        // packed [16][512][8] 128KB
    __half* W2p  = (__half*)(ws + 667648);        // packed [64][128][8] 128KB
    __half* WXg  = (__half*)(ws + 798720);        // [512][1024] fp16 1MB

    k_front<<<336 + noff, 256, 0, stream>>>(Wq, bq, Wk, Wv, Wo, bv, W1, W2,
                                            mol, N, noff,
                                            offs, WVOp, WQKp, bqk, bvoP, W1p, W2p);
    k_attn<<<BMOL, 512, 0, stream>>>(AF, offs, picked, WQKp, bqk, WXg);
    k_tail<<<128, 512, 0, stream>>>(AF, offs, picked, WXg, WVOp, bvoP, bo,
                                    g1, be1, W1p, b1, W2p, b2, g2, be2,
                                    (float*)d_out);
}